// Round 19
// baseline (48.748 us; speedup 1.0000x reference)
//
#include <hip/hip_runtime.h>
#include <hip/hip_bf16.h>

#define H_IN 4096
#define W_IN 4096
#define KH 15
#define KW 15
#define OH (H_IN - KH + 1)   // 4082
#define OW (W_IN - KW + 1)   // 4082

#define BM 64                // output rows per block (4 waves x 16)
#define BN 64                // output cols per block (NJ=4 j-frags)
#define NJ (BN / 16)         // 4
#define SROWS (BM + KH - 1)  // 78 staged rows
#define SG 10                // 16B granules staged per row (80 bf16 cols)
#define SGRAN 16             // granules per LDS row (mult of 8 -> XOR swizzle legal)
#define SSTR (SGRAN * 8)     // 128 ushort row stride (256 B)
#define STAGE_N (SROWS * SG) // 780 16B items
#define NIT 4                // ceil(STAGE_N / 256)

typedef __attribute__((ext_vector_type(8))) short short8;   // MFMA A/B frag
typedef __attribute__((ext_vector_type(4))) float f32x4;    // MFMA C/D frag

__device__ __forceinline__ ushort f2bf(float f) {
    __hip_bfloat16 h = __float2bfloat16(f);       // native v_cvt path
    return __builtin_bit_cast(ushort, h);
}

// ---- prep: build banded Toeplitz weight frags into workspace (15 KB) ----
// B[k][j] = w[kh][k-j]; frag layout: lane l holds B[8*(l>>4)+u][l&15], u=0..7
__global__ __launch_bounds__(256)
void build_wfrags(const float* __restrict__ Wt, ushort* __restrict__ Bw)
{
    int idx = blockIdx.x * 256 + threadIdx.x;
    if (idx < KH * 64) {
        int kh = idx >> 6, l = idx & 63;
        int j = l & 15, k0 = (l >> 4) * 8;
        union { ushort u[8]; uint4 v; } t;
#pragma unroll
        for (int u = 0; u < 8; ++u) {
            int kw = k0 + u - j;
            t.u[u] = f2bf((kw >= 0 && kw < KW) ? Wt[kh * KW + kw] : 0.0f);
        }
        *reinterpret_cast<uint4*>(&Bw[idx * 8]) = t.v;
    }
}

// 64-reg budget -> 8 waves/SIMD; LDS 19968 B -> 8 blocks; both caps = 32 waves/CU
__global__ __launch_bounds__(256, 8)
void conv2d_mfma_bf16(const float* __restrict__ X,
                      const ushort* __restrict__ Bw,
                      const float* __restrict__ Bias,
                      float* __restrict__ Out)
{
    __shared__ ushort s_x[SROWS * SSTR];     // 19968 B

    const int tid = threadIdx.x;
    const int l = tid & 63;
    const int w = tid >> 6;
    const int ox0 = blockIdx.x * BN;
    const int oy0 = blockIdx.y * BM;
    const bool xint = (ox0 + SG * 8 <= W_IN);

    // ---- stage phase A: issue ALL tile loads (T14 split, one vmcnt drain) ----
    float4 va[NIT], vb[NIT];                 // 32 VGPR
#pragma unroll
    for (int k = 0; k < NIT; ++k) {
        int i = tid + 256 * k;
        if (i < STAGE_N) {
            int r = i / SG;
            int g = i % SG;
            int gy = min(oy0 + r, H_IN - 1);
            const float* rp = X + (size_t)gy * W_IN;
            int gx = ox0 + g * 8;
            if (xint) {
                va[k] = *reinterpret_cast<const float4*>(rp + gx);
                vb[k] = *reinterpret_cast<const float4*>(rp + gx + 4);
            } else {
                va[k].x = rp[min(gx + 0, W_IN - 1)];
                va[k].y = rp[min(gx + 1, W_IN - 1)];
                va[k].z = rp[min(gx + 2, W_IN - 1)];
                va[k].w = rp[min(gx + 3, W_IN - 1)];
                vb[k].x = rp[min(gx + 4, W_IN - 1)];
                vb[k].y = rp[min(gx + 5, W_IN - 1)];
                vb[k].z = rp[min(gx + 6, W_IN - 1)];
                vb[k].w = rp[min(gx + 7, W_IN - 1)];
            }
        }
    }
    // ---- stage phase B: convert + swizzled 16B LDS writes (rule #21: both sides) ----
#pragma unroll
    for (int k = 0; k < NIT; ++k) {
        int i = tid + 256 * k;
        if (i < STAGE_N) {
            int r = i / SG;
            int g = i % SG;
            uint4 pk;
            pk.x = (uint32_t)f2bf(va[k].x) | ((uint32_t)f2bf(va[k].y) << 16);
            pk.y = (uint32_t)f2bf(va[k].z) | ((uint32_t)f2bf(va[k].w) << 16);
            pk.z = (uint32_t)f2bf(vb[k].x) | ((uint32_t)f2bf(vb[k].y) << 16);
            pk.w = (uint32_t)f2bf(vb[k].z) | ((uint32_t)f2bf(vb[k].w) << 16);
            *reinterpret_cast<uint4*>(&s_x[r * SSTR + ((g ^ (r & 7)) << 3)]) = pk;
        }
    }
    __syncthreads();       // only barrier in the kernel

    // ---- compute: per kh {1 B-load (L1-hot), 4 swizzled A-reads, 4 MFMAs} ----
    const ushort* const bbase = Bw + l * 8;
    const int r0  = w * 16 + (l & 15);       // A local row base
    const int gc0 = l >> 4;                  // A granule offset within j-pair

    f32x4 acc[NJ];
#pragma unroll
    for (int j = 0; j < NJ; ++j) acc[j] = (f32x4){0.f, 0.f, 0.f, 0.f};

#pragma unroll
    for (int kh = 0; kh < KH; ++kh) {
        short8 bf = *reinterpret_cast<const short8*>(bbase + kh * 64 * 8);
        const int rr = r0 + kh;
        const int rowb = rr * SSTR;
        const int x7 = rr & 7;
#pragma unroll
        for (int j = 0; j < NJ; ++j) {
            int off = rowb + (((2 * j + gc0) ^ x7) << 3);
            short8 a = *reinterpret_cast<const short8*>(&s_x[off]);
            acc[j] = __builtin_amdgcn_mfma_f32_16x16x32_bf16(a, bf, acc[j], 0, 0, 0);
        }
    }

    // ---- store: C/D layout col=lane&15, row=(lane>>4)*4+r ----
    const float b = Bias[0];
    const int orow0 = oy0 + w * 16 + (l >> 4) * 4;
    const int ocol  = ox0 + (l & 15);
    if (oy0 + BM <= OH && ox0 + BN <= OW) {
        float* op0 = &Out[(size_t)orow0 * OW + ocol];
#pragma unroll
        for (int j = 0; j < NJ; ++j) {
#pragma unroll
            for (int r = 0; r < 4; ++r)
                op0[(size_t)r * OW + j * 16] = acc[j][r] + b;
        }
    } else {
#pragma unroll
        for (int j = 0; j < NJ; ++j) {
            int oc = ocol + j * 16;
            if (oc < OW) {
#pragma unroll
                for (int r = 0; r < 4; ++r) {
                    int orow = orow0 + r;
                    if (orow < OH)
                        Out[(size_t)orow * OW + oc] = acc[j][r] + b;
                }
            }
        }
    }
}

extern "C" void kernel_launch(void* const* d_in, const int* in_sizes, int n_in,
                              void* d_out, int out_size, void* d_ws, size_t ws_size,
                              hipStream_t stream)
{
    const float* X    = (const float*)d_in[0];
    const float* Wt   = (const float*)d_in[1];
    const float* Bias = (const float*)d_in[2];
    float* Out        = (float*)d_out;
    ushort* Bw        = (ushort*)d_ws;        // 15*64*8 ushort = 15360 B

    hipLaunchKernelGGL(build_wfrags, dim3((KH * 64 + 255) / 256), dim3(256), 0, stream,
                       Wt, Bw);

    dim3 grid((OW + BN - 1) / BN,    // 64
              (OH + BM - 1) / BM);   // 64   -> 4096 blocks, 16 per CU
    dim3 block(256);
    hipLaunchKernelGGL(conv2d_mfma_bf16, grid, block, 0, stream, X, Bw, Bias, Out);
}